// Round 16
// baseline (163.073 us; speedup 1.0000x reference)
//
#include <hip/hip_runtime.h>
#include <hip/hip_fp16.h>
#include <math.h>

#define NN 50000
#define NE 800000
#define HD 128
#define NG 256
#define SCAN_B 196     // ceil(NN/256)
#define NODE_B 12500   // NN/4
#define HIST_B 3125    // NE/256
#define GEM_B 782      // ceil(NN/64)
#define ZQ2 8192       // 131072/16 uint4 for pooled
#define WP_HIST0 73    // wpack: 0..39 weights, 40 prevec, 41..72 zero, 73.. hist

typedef unsigned int u32;
typedef unsigned short u16;
typedef __attribute__((ext_vector_type(8))) short bf16x8;
typedef __attribute__((ext_vector_type(4))) float f32x4;
typedef __attribute__((ext_vector_type(2))) float f32x2;

__device__ __forceinline__ float wave_allsum(float v) {
#pragma unroll
  for (int m = 1; m < 64; m <<= 1) v += __shfl_xor(v, m, 64);
  return v;
}
__device__ __forceinline__ float bcastf(float v, int t) {
  return __int_as_float(__builtin_amdgcn_readlane(__float_as_int(v), t));
}
__device__ __forceinline__ u32 f2b_bits(float f) {  // RNE float->bf16 bits
  u32 u = __float_as_uint(f);
  return (u + 0x7fffu + ((u >> 16) & 1u)) >> 16;
}
__device__ __forceinline__ u32 cvtpk_bf16(float lo, float hi) {
  u32 r;
  asm("v_cvt_pk_bf16_f32 %0, %1, %2" : "=v"(r) : "v"(lo), "v"(hi));
  return r;
}
__device__ __forceinline__ f32x2 splat2(float v) { return (f32x2){v, v}; }
__device__ __forceinline__ f32x2 pkfma(f32x2 a, f32x2 b, f32x2 c) {
  return a * b + c;  // fp-contract -> v_pk_fma_f32
}

// ---- blocks 0..39: weight pack; 40: prevec; 41..72: zero pooled;
//      73..: degree histogram (slot = atomic return) ----
__global__ __launch_bounds__(256) void k_wpack(
    const float* __restrict__ gcn_w, const float* __restrict__ pam_w,
    const float* __restrict__ pm_w2, const float* __restrict__ fus_w,
    const float* __restrict__ pam_b, const float* __restrict__ att_w,
    const float* __restrict__ att_b, const float* __restrict__ pm_b2,
    u16* __restrict__ Bg, u16* __restrict__ Bl, u16* __restrict__ Bf,
    float* __restrict__ vi, float* __restrict__ vj,
    float* __restrict__ consts, float* __restrict__ bsumv,
    uint4* __restrict__ zr2, const int* __restrict__ ei,
    int* __restrict__ cnt, u16* __restrict__ slot16) {
  if (blockIdx.x >= WP_HIST0) {  // histogram
    const int e = (blockIdx.x - WP_HIST0) * 256 + threadIdx.x;
    if (e < NE) slot16[e] = (u16)atomicAdd(&cnt[ei[NE + e]], 1);
    return;
  }
  if (blockIdx.x >= 41) {  // zero pooled
    const int zi = (blockIdx.x - 41) * 256 + threadIdx.x;
    if (zi < ZQ2) zr2[zi] = (uint4){0u, 0u, 0u, 0u};
    return;
  }
  if (blockIdx.x == 40) {  // prevec
    const int t = threadIdx.x;
    const int k = t & 127;
    const float* w = att_w + (t >> 7) * HD;
    float s = 0.f;
    for (int h = 0; h < HD; ++h) s = fmaf(pam_w[k * HD + h], w[h], s);
    if (t < 128) {
      vi[k] = s;
      bsumv[k] = pam_b[k] + pm_b2[k];
    } else {
      vj[k] = s;
    }
    if (t < 64) {
      float p = fmaf(pam_b[t], att_w[t], pam_b[t + 64] * att_w[t + 64]);
      p = wave_allsum(p);
      if (t == 0) consts[0] = p + att_b[0];
    } else if (t < 128) {
      const int l = t - 64;
      float p =
          fmaf(pam_b[l], att_w[HD + l], pam_b[l + 64] * att_w[HD + 64 + l]);
      p = wave_allsum(p);
      if (l == 0) consts[1] = p;
    }
    return;
  }
  const int t = blockIdx.x * 256 + threadIdx.x;
  const float* W;
  u16* dst;
  if (t < 2048) {  // gcn_w: K=128 -> 16 kb
    const int kb = t >> 7, n = t & 127;
    W = gcn_w + (size_t)kb * 8 * HD + n;
    dst = Bg + (size_t)t * 8;
  } else if (t < 6144) {  // [pam_w; pm_w2]: K=256 -> 32 kb
    const int u = t - 2048;
    const int kb = u >> 7, n = u & 127;
    W = ((kb < 16) ? (pam_w + (size_t)kb * 8 * HD)
                   : (pm_w2 + (size_t)(kb - 16) * 8 * HD)) +
        n;
    dst = Bl + (size_t)u * 8;
  } else {  // fus_w: K=256 -> 32 kb
    const int u = t - 6144;
    const int kb = u >> 7, n = u & 127;
    W = fus_w + (size_t)kb * 8 * HD + n;
    dst = Bf + (size_t)u * 8;
  }
  union {
    u16 o[8];
    uint4 v;
  } pk;
#pragma unroll
  for (int i = 0; i < 8; ++i) pk.o[i] = (u16)f2b_bits(W[i * HD]);
  *(uint4*)dst = pk.v;
}

// ---- per-256-block sums of cnt ----
__global__ __launch_bounds__(256) void k_scan1(const int* __restrict__ cnt,
                                               int* __restrict__ bsum) {
  const int i = blockIdx.x * 256 + threadIdx.x;
  int v = (i < NN) ? cnt[i] : 0;
#pragma unroll
  for (int m = 1; m < 64; m <<= 1) v += __shfl_xor(v, m, 64);
  __shared__ int s[4];
  if ((threadIdx.x & 63) == 0) s[threadIdx.x >> 6] = v;
  __syncthreads();
  if (threadIdx.x == 0) bsum[blockIdx.x] = s[0] + s[1] + s[2] + s[3];
}

// ---- blocks <SCAN_B: scan (offs, dinv). blocks >=SCAN_B: node pass
//      (y = dinv*x fp8, att dots, posadj incl. f16{aj,sdeg}) — independent
//      of the scan, only needs cnt. ----
__global__ __launch_bounds__(256) void k_scan23(
    const int* __restrict__ cnt, const int* __restrict__ bsum,
    const float* __restrict__ pos, const float* __restrict__ x,
    const float* __restrict__ vi, const float* __restrict__ vj,
    const float* __restrict__ consts, int* __restrict__ offs,
    float* __restrict__ dinv, float4* __restrict__ posadj,
    u16* __restrict__ xq, float* __restrict__ ai_arr) {
  if (blockIdx.x >= SCAN_B) {  // node pass
    const int wave = threadIdx.x >> 6, lane = threadIdx.x & 63;
    const int i = (blockIdx.x - SCAN_B) * 4 + wave;
    if (i >= NN) return;
    const float2 v = *(const float2*)&x[(size_t)i * HD + lane * 2];
    const int c = cnt[i];
    const float dv = __builtin_amdgcn_rsqf((float)c + 1.0f);
    const u32 q =
        __builtin_amdgcn_cvt_pk_fp8_f32(dv * v.x, dv * v.y, 0u, false);
    xq[(size_t)i * 64 + lane] = (u16)q;
    const float2 a = *(const float2*)&vi[lane * 2];
    const float2 b = *(const float2*)&vj[lane * 2];
    float si = wave_allsum(fmaf(v.x, a.x, v.y * a.y));
    float sj = wave_allsum(fmaf(v.x, b.x, v.y * b.y));
    if (lane == 0) {
      ai_arr[i] = si + consts[0];
      const u32 wb =
          (u32)__half_as_ushort(__float2half(sj + consts[1])) |
          ((u32)__half_as_ushort(__float2half(sqrtf((float)c + 1.f))) << 16);
      posadj[i] = make_float4(pos[3 * i], pos[3 * i + 1], pos[3 * i + 2],
                              __uint_as_float(wb));
    }
    return;
  }
  __shared__ int s[256];
  const int t = threadIdx.x;
  const int bv = (t < SCAN_B) ? bsum[t] : 0;
  s[t] = bv;
  __syncthreads();
  for (int d = 1; d < 256; d <<= 1) {
    int add = (t >= d) ? s[t - d] : 0;
    __syncthreads();
    s[t] += add;
    __syncthreads();
  }
  const int bpre = (blockIdx.x > 0) ? s[blockIdx.x - 1] : 0;
  __syncthreads();
  const int i = blockIdx.x * 256 + t;
  const int v = (i < NN) ? cnt[i] : 0;
  s[t] = v;
  __syncthreads();
  for (int d = 1; d < 256; d <<= 1) {
    int add = (t >= d) ? s[t - d] : 0;
    __syncthreads();
    s[t] += add;
    __syncthreads();
  }
  if (i < NN) {
    offs[i] = bpre + s[t] - v;
    dinv[i] = __builtin_amdgcn_rsqf((float)v + 1.0f);
  }
}

// ---- CSR scatter (u16 payload, no atomics) | graph counts ----
__global__ __launch_bounds__(256) void k_scatgc(
    const int* __restrict__ ei, const int* __restrict__ offs,
    const u16* __restrict__ slot16, u16* __restrict__ csr16,
    const int* __restrict__ batch, float* __restrict__ counts) {
  if (blockIdx.x < HIST_B) {  // scatter: plain u16 stores (L2-resident)
    const int e = blockIdx.x * 256 + threadIdx.x;
    if (e < NE) {
      const int d = ei[NE + e];
      csr16[offs[d] + slot16[e]] = (u16)ei[e];
    }
    return;
  }
  // graph counts via binary search
  const int g = threadIdx.x;
  int lo = 0, hi = NN;
  while (lo < hi) {
    const int mid = (lo + hi) >> 1;
    if (batch[mid] < g) lo = mid + 1; else hi = mid;
  }
  const int b0 = lo;
  hi = NN;
  while (lo < hi) {
    const int mid = (lo + hi) >> 1;
    if (batch[mid] <= g) lo = mid + 1; else hi = mid;
  }
  counts[g] = (float)(lo - b0);
}

// ------------- per-node edge aggregation (1 wave / node) -------------------
// R14 best-measured variant; csr now u16.
__global__ __launch_bounds__(256) void k_agg(
    const u16* __restrict__ xq, const float4* __restrict__ posadj,
    const u16* __restrict__ csr16, const int* __restrict__ offs,
    const int* __restrict__ cnt, const float* __restrict__ ai_arr,
    const float* __restrict__ pm_w1, const float* __restrict__ pm_b1,
    u32* __restrict__ ZG, u32* __restrict__ XT, float* __restrict__ sa_out) {
  const int wave = threadIdx.x >> 6, lane = threadIdx.x & 63;
  const int i = blockIdx.x * 4 + wave;
  if (i >= NN) return;
  const int c0 = lane * 2;

  const f32x2 w1x = *(const f32x2*)&pm_w1[c0];
  const f32x2 w1y = *(const f32x2*)&pm_w1[HD + c0];
  const f32x2 w1z = *(const f32x2*)&pm_w1[2 * HD + c0];
  const f32x2 b1 = *(const f32x2*)&pm_b1[c0];
  const float ai = ai_arr[i];
  const float4 pi = posadj[i];

  f32x2 zg = {0.f, 0.f}, xa = {0.f, 0.f}, tt = {0.f, 0.f};
  float sa = 0.f;
  const int b = offs[i], e = b + cnt[i];
  for (int base = b; base < e; base += 64) {
    const int mm = min(64, e - base);
    const int sk = (int)csr16[base + ((lane < mm) ? lane : 0)];
    const float4 pa = posadj[sk];  // one scattered 16B gather per edge
    const u32 wb = __float_as_uint(pa.w);
    const float aj = __half2float(__ushort_as_half((u16)(wb & 0xffffu)));
    const float sdeg = __half2float(__ushort_as_half((u16)(wb >> 16)));
    float attk = __builtin_amdgcn_rcpf(1.f + __expf(-(ai + aj)));
    const float apk = attk * sdeg;  // att' = att*sdeg
    const float dxk = pi.x - pa.x;
    const float dyk = pi.y - pa.y;
    const float dzk = pi.z - pa.z;
    if (lane >= mm) attk = 0.f;
    sa += wave_allsum(attk);

    for (int s16 = 0; s16 < mm; s16 += 16) {
      const int n16 = min(16, mm - s16);
      u32 rr[16];
#pragma unroll
      for (int u = 0; u < 16; ++u) {
        if (u < n16) {
          const int s = __builtin_amdgcn_readlane(sk, s16 + u);
          rr[u] = *(xq + ((size_t)s << 6) + lane);  // uniform base + lane
        }
      }
#pragma unroll
      for (int u = 0; u < 16; ++u) {
        if (u < n16) {
          const int T = s16 + u;
          const float att = bcastf(attk, T);
          const float ap = bcastf(apk, T);
          const float dx = bcastf(dxk, T);
          const float dy = bcastf(dyk, T);
          const float dz = bcastf(dzk, T);
          const f32x2 y = __builtin_amdgcn_cvt_pk_f32_fp8(rr[u], false);
          zg += y;
          xa = pkfma(splat2(ap), y, xa);
          f32x2 gg = pkfma(splat2(dz), w1z,
                           pkfma(splat2(dy), w1y,
                                 pkfma(splat2(dx), w1x, b1)));
          gg = __builtin_elementwise_max(gg, splat2(0.f));
          tt = pkfma(splat2(att), gg, tt);
        }
      }
    }
  }
  const u32 xi = *(xq + ((size_t)i << 6) + lane);  // self term: y_i
  zg += __builtin_amdgcn_cvt_pk_f32_fp8(xi, false);

  ZG[(size_t)i * 64 + lane] = cvtpk_bf16(zg.x, zg.y);
  XT[(size_t)i * 128 + lane] = cvtpk_bf16(xa.x, xa.y);
  XT[(size_t)i * 128 + 64 + lane] = cvtpk_bf16(tt.x, tt.y);
  if (lane == 0) sa_out[i] = sa;
}

// ---- GEMM phase with DEPTH-2 prefetch (3-buffer ping-pong, static idx). ----
template <int K16>
__device__ __forceinline__ void phase_g2(const u16* __restrict__ pa,
                                         const u16* __restrict__ pb0,
                                         f32x4 acc[8]) {
  bf16x8 a[3], b[3][8];
#pragma unroll
  for (int p = 0; p < 2; ++p) {  // prologue: k0=0,1 in flight (K16 >= 2)
    a[p] = *(const bf16x8*)(pa + p * 32);
    const u16* pn = pb0 + (size_t)p * 4096;
#pragma unroll
    for (int cf = 0; cf < 8; ++cf) b[p][cf] = *(const bf16x8*)(pn + cf * 128);
  }
#pragma unroll
  for (int k0 = 0; k0 < K16; ++k0) {
    if (k0 + 2 < K16) {
      const int nb = (k0 + 2) % 3;
      a[nb] = *(const bf16x8*)(pa + (k0 + 2) * 32);
      const u16* pn = pb0 + (size_t)(k0 + 2) * 4096;
#pragma unroll
      for (int cf = 0; cf < 8; ++cf)
        b[nb][cf] = *(const bf16x8*)(pn + cf * 128);
    }
    const int cb = k0 % 3;
#pragma unroll
    for (int cf = 0; cf < 8; ++cf)
      acc[cf] = __builtin_amdgcn_mfma_f32_16x16x32_bf16(a[cb], b[cb][cf],
                                                        acc[cf], 0, 0, 0);
  }
}

// ---- fused dense tail, 64-row tiles, 4 waves, each wave owns 16 rows ----
__global__ __launch_bounds__(256, 3) void k_gemms(
    const u16* __restrict__ ZG, const u16* __restrict__ XT,
    const u16* __restrict__ Bg, const u16* __restrict__ Bl,
    const u16* __restrict__ Bf, const float* __restrict__ dinv,
    const float* __restrict__ sa, const float* __restrict__ gcn_b,
    const float* __restrict__ bsumv, const float* __restrict__ fus_b,
    const int* __restrict__ batch, float* __restrict__ pooled) {
  __shared__ u16 T[64 * 256];  // 32KB bf16 [gl|local]; reused as f32 F[64][128]
  __shared__ int batch_lds[64];
  const int n0 = blockIdx.x * 64;
  const int t = threadIdx.x, lane = t & 63, w = t >> 6;
  const int m = lane & 15, g = lane >> 4;
  const int r0 = w * 16;

  if (t < 64) batch_lds[t] = (n0 + t < NN) ? batch[n0 + t] : -1;

  const int rowA = min(n0 + r0 + m, NN - 1);
  f32x4 acc[8];

  // ---- phase A: gl = relu(dinv*(ZG@gcn_w) + gcn_b) -> T cols 0..127 ----
#pragma unroll
  for (int cf = 0; cf < 8; ++cf) acc[cf] = (f32x4){0.f, 0.f, 0.f, 0.f};
  phase_g2<4>(ZG + (size_t)rowA * 128 + g * 8, Bg + ((size_t)g * HD + m) * 8,
              acc);
#pragma unroll
  for (int j = 0; j < 4; ++j) {
    const int rl = r0 + g * 4 + j;
    const float dv = dinv[min(n0 + rl, NN - 1)];
#pragma unroll
    for (int cf = 0; cf < 8; ++cf) {
      const float v = fmaxf(fmaf(dv, acc[cf][j], gcn_b[cf * 16 + m]), 0.f);
      T[rl * 256 + ((cf * 16 + m) ^ ((rl & 7) << 3))] = (u16)f2b_bits(v);
    }
  }

  // ---- phase B: local = relu(XT@Bl + sa*bsum) -> T cols 128..255 ----
#pragma unroll
  for (int cf = 0; cf < 8; ++cf) acc[cf] = (f32x4){0.f, 0.f, 0.f, 0.f};
  phase_g2<8>(XT + (size_t)rowA * 256 + g * 8, Bl + ((size_t)g * HD + m) * 8,
              acc);
#pragma unroll
  for (int j = 0; j < 4; ++j) {
    const int rl = r0 + g * 4 + j;
    const float sv = sa[min(n0 + rl, NN - 1)];
#pragma unroll
    for (int cf = 0; cf < 8; ++cf) {
      const float v = fmaxf(fmaf(sv, bsumv[cf * 16 + m], acc[cf][j]), 0.f);
      T[rl * 256 + ((128 + cf * 16 + m) ^ ((rl & 7) << 3))] = (u16)f2b_bits(v);
    }
  }

  // ---- phase C: fused = relu([gl|local]@fus_w + fus_b), A from LDS (own
  //      rows; no barrier needed), depth-2 B prefetch ----
  const int x0m = (m & 7) << 3;
  const u16* rowT = &T[(r0 + m) * 256];
  const u16* pbC = Bf + ((size_t)g * HD + m) * 8;
#pragma unroll
  for (int cf = 0; cf < 8; ++cf) acc[cf] = (f32x4){0.f, 0.f, 0.f, 0.f};
  {
    bf16x8 a[3], b[3][8];
#pragma unroll
    for (int p = 0; p < 2; ++p) {
      a[p] = *(const bf16x8*)&rowT[(g * 8 + p * 32) ^ x0m];
      const u16* pn = pbC + (size_t)p * 4096;
#pragma unroll
      for (int cf = 0; cf < 8; ++cf) b[p][cf] = *(const bf16x8*)(pn + cf * 128);
    }
#pragma unroll
    for (int k0 = 0; k0 < 8; ++k0) {
      if (k0 + 2 < 8) {
        const int nb = (k0 + 2) % 3;
        a[nb] = *(const bf16x8*)&rowT[(g * 8 + (k0 + 2) * 32) ^ x0m];
        const u16* pn = pbC + (size_t)(k0 + 2) * 4096;
#pragma unroll
        for (int cf = 0; cf < 8; ++cf)
          b[nb][cf] = *(const bf16x8*)(pn + cf * 128);
      }
      const int cb = k0 % 3;
#pragma unroll
      for (int cf = 0; cf < 8; ++cf)
        acc[cf] = __builtin_amdgcn_mfma_f32_16x16x32_bf16(a[cb], b[cb][cf],
                                                          acc[cf], 0, 0, 0);
    }
  }
  float* F = (float*)T;  // overwrite own rows only
#pragma unroll
  for (int j = 0; j < 4; ++j) {
    const int rl = r0 + g * 4 + j;
#pragma unroll
    for (int cf = 0; cf < 8; ++cf)
      F[rl * 128 + ((cf * 16 + m) ^ ((rl & 12) << 2))] =
          fmaxf(acc[cf][j] + fus_b[cf * 16 + m], 0.f);
  }
  __syncthreads();

  // ---- segment pooling over sorted batch ids ----
  const int col = t & 127;
  const int q = t >> 7;
  int seg = -1;
  float run = 0.f;
  for (int r = q * 32; r < q * 32 + 32; ++r) {
    const int bg = batch_lds[r];
    const float v = F[r * 128 + (col ^ ((r & 12) << 2))];
    if (bg != seg) {
      if (seg >= 0) atomicAdd(&pooled[seg * HD + col], run);
      seg = bg;
      run = 0.f;
    }
    if (bg >= 0) run += v;
  }
  if (seg >= 0) atomicAdd(&pooled[seg * HD + col], run);
}

// ---------------- head: out = relu(pooled/cnt @ l1)@l2 ----------------
__global__ __launch_bounds__(64) void k_head(const float* __restrict__ pooled,
                                             const float* __restrict__ counts,
                                             const float* __restrict__ l1w,
                                             const float* __restrict__ l1b,
                                             const float* __restrict__ l2w,
                                             const float* __restrict__ l2b,
                                             float* __restrict__ out) {
  const int g = blockIdx.x, j = threadIdx.x;
  const float inv = __builtin_amdgcn_rcpf(fmaxf(counts[g], 1.f));
  float acc = l1b[j];
  for (int k = 0; k < HD; ++k)
    acc = fmaf(pooled[g * HD + k] * inv, l1w[k * 64 + j], acc);
  float v = fmaxf(acc, 0.f) * l2w[j];
  v = wave_allsum(v);
  if (j == 0) out[g] = v + l2b[0];
}

extern "C" void kernel_launch(void* const* d_in, const int* in_sizes, int n_in,
                              void* d_out, int out_size, void* d_ws,
                              size_t ws_size, hipStream_t stream) {
  const float* x = (const float*)d_in[0];
  const float* pos = (const float*)d_in[1];
  const int* ei = (const int*)d_in[2];
  const int* batch = (const int*)d_in[3];
  const float* gcn_w = (const float*)d_in[4];
  const float* gcn_b = (const float*)d_in[5];
  const float* pam_w = (const float*)d_in[6];
  const float* pam_b = (const float*)d_in[7];
  const float* pm_w1 = (const float*)d_in[8];
  const float* pm_b1 = (const float*)d_in[9];
  const float* pm_w2 = (const float*)d_in[10];
  const float* pm_b2 = (const float*)d_in[11];
  const float* att_w = (const float*)d_in[12];
  const float* att_b = (const float*)d_in[13];
  const float* fus_w = (const float*)d_in[14];
  const float* fus_b = (const float*)d_in[15];
  const float* l1_w = (const float*)d_in[16];
  const float* l1_b = (const float*)d_in[17];
  const float* l2_w = (const float*)d_in[18];
  const float* l2_b = (const float*)d_in[19];
  float* out = (float*)d_out;

  size_t off = 0;
  auto alloc = [&](size_t bytes) {
    void* p = (char*)d_ws + off;
    off += (bytes + 255) & ~size_t(255);
    return p;
  };
  u16* xq = (u16*)alloc((size_t)NN * 64 * 2);  // y = dinv*x, fp8 e4m3 (6.4MB)
  u32* ZG = (u32*)alloc((size_t)NN * 64 * 4);
  u32* XT = (u32*)alloc((size_t)NN * 128 * 4);
  float* sa = (float*)alloc((size_t)NN * 4);
  float* ai = (float*)alloc((size_t)NN * 4);
  float* dinv = (float*)alloc((size_t)NN * 4);
  float4* posadj = (float4*)alloc((size_t)NN * 16);  // {x,y,z, f16{aj,sdeg}}
  float* pooled = (float*)alloc((size_t)NG * HD * 4);
  float* counts = (float*)alloc((size_t)NG * 4);
  int* cnt = (int*)alloc((size_t)NN * 4);  // zeroed via memsetAsync
  int* offs = (int*)alloc((size_t)NN * 4);
  u16* csr16 = (u16*)alloc((size_t)NE * 2);
  u16* slot16 = (u16*)alloc((size_t)NE * 2);
  int* bsum = (int*)alloc((size_t)SCAN_B * 4);
  u16* Bg = (u16*)alloc((size_t)16 * 128 * 8 * 2);
  u16* Bl = (u16*)alloc((size_t)32 * 128 * 8 * 2);
  u16* Bf = (u16*)alloc((size_t)32 * 128 * 8 * 2);
  float* vi = (float*)alloc(128 * 4);
  float* vj = (float*)alloc(128 * 4);
  float* consts = (float*)alloc(2 * 4);
  float* bsumv = (float*)alloc(128 * 4);

  hipMemsetAsync(cnt, 0, NN * 4, stream);
  k_wpack<<<WP_HIST0 + HIST_B, 256, 0, stream>>>(
      gcn_w, pam_w, pm_w2, fus_w, pam_b, att_w, att_b, pm_b2, Bg, Bl, Bf, vi,
      vj, consts, bsumv, (uint4*)pooled, ei, cnt, slot16);
  k_scan1<<<SCAN_B, 256, 0, stream>>>(cnt, bsum);
  k_scan23<<<SCAN_B + NODE_B, 256, 0, stream>>>(cnt, bsum, pos, x, vi, vj,
                                                consts, offs, dinv, posadj,
                                                xq, ai);
  k_scatgc<<<HIST_B + 1, 256, 0, stream>>>(ei, offs, slot16, csr16, batch,
                                           counts);
  k_agg<<<NODE_B, 256, 0, stream>>>(xq, posadj, csr16, offs, cnt, ai, pm_w1,
                                    pm_b1, ZG, XT, sa);
  k_gemms<<<GEM_B, 256, 0, stream>>>((const u16*)ZG, (const u16*)XT, Bg, Bl,
                                     Bf, dinv, sa, gcn_b, bsumv, fus_b, batch,
                                     pooled);
  k_head<<<NG, 64, 0, stream>>>(pooled, counts, l1_w, l1_b, l2_w, l2_b, out);
}

// Round 17
// 157.908 us; speedup vs baseline: 1.0327x; 1.0327x over previous
//
#include <hip/hip_runtime.h>
#include <hip/hip_fp16.h>
#include <math.h>

#define NN 50000
#define NE 800000
#define HD 128
#define NG 256
#define SCAN_B 196     // ceil(NN/256)
#define NODE_B 12500   // NN/4
#define HIST_B 3125    // NE/256
#define GEM_B 782      // ceil(NN/64)
#define ZQ2 8192       // 131072/16 uint4 for pooled
#define WP_HIST0 73    // wpack: 0..39 weights, 40 prevec, 41..72 zero, 73.. hist

typedef unsigned int u32;
typedef unsigned short u16;
typedef __attribute__((ext_vector_type(8))) short bf16x8;
typedef __attribute__((ext_vector_type(4))) float f32x4;
typedef __attribute__((ext_vector_type(2))) float f32x2;

__device__ __forceinline__ float wave_allsum(float v) {
#pragma unroll
  for (int m = 1; m < 64; m <<= 1) v += __shfl_xor(v, m, 64);
  return v;
}
__device__ __forceinline__ float bcastf(float v, int t) {
  return __int_as_float(__builtin_amdgcn_readlane(__float_as_int(v), t));
}
__device__ __forceinline__ u32 f2b_bits(float f) {  // RNE float->bf16 bits
  u32 u = __float_as_uint(f);
  return (u + 0x7fffu + ((u >> 16) & 1u)) >> 16;
}
__device__ __forceinline__ u32 cvtpk_bf16(float lo, float hi) {
  u32 r;
  asm("v_cvt_pk_bf16_f32 %0, %1, %2" : "=v"(r) : "v"(lo), "v"(hi));
  return r;
}
__device__ __forceinline__ f32x2 splat2(float v) { return (f32x2){v, v}; }
__device__ __forceinline__ f32x2 pkfma(f32x2 a, f32x2 b, f32x2 c) {
  return a * b + c;  // fp-contract -> v_pk_fma_f32
}

// ---- blocks 0..39: weight pack; 40: prevec; 41..72: zero pooled;
//      73..: degree histogram (slot = atomic return) ----
__global__ __launch_bounds__(256) void k_wpack(
    const float* __restrict__ gcn_w, const float* __restrict__ pam_w,
    const float* __restrict__ pm_w2, const float* __restrict__ fus_w,
    const float* __restrict__ pam_b, const float* __restrict__ att_w,
    const float* __restrict__ att_b, const float* __restrict__ pm_b2,
    u16* __restrict__ Bg, u16* __restrict__ Bl, u16* __restrict__ Bf,
    float* __restrict__ vi, float* __restrict__ vj,
    float* __restrict__ consts, float* __restrict__ bsumv,
    uint4* __restrict__ zr2, const int* __restrict__ ei,
    int* __restrict__ cnt, u16* __restrict__ slot16) {
  if (blockIdx.x >= WP_HIST0) {  // histogram
    const int e = (blockIdx.x - WP_HIST0) * 256 + threadIdx.x;
    if (e < NE) slot16[e] = (u16)atomicAdd(&cnt[ei[NE + e]], 1);
    return;
  }
  if (blockIdx.x >= 41) {  // zero pooled
    const int zi = (blockIdx.x - 41) * 256 + threadIdx.x;
    if (zi < ZQ2) zr2[zi] = (uint4){0u, 0u, 0u, 0u};
    return;
  }
  if (blockIdx.x == 40) {  // prevec
    const int t = threadIdx.x;
    const int k = t & 127;
    const float* w = att_w + (t >> 7) * HD;
    float s = 0.f;
    for (int h = 0; h < HD; ++h) s = fmaf(pam_w[k * HD + h], w[h], s);
    if (t < 128) {
      vi[k] = s;
      bsumv[k] = pam_b[k] + pm_b2[k];
    } else {
      vj[k] = s;
    }
    if (t < 64) {
      float p = fmaf(pam_b[t], att_w[t], pam_b[t + 64] * att_w[t + 64]);
      p = wave_allsum(p);
      if (t == 0) consts[0] = p + att_b[0];
    } else if (t < 128) {
      const int l = t - 64;
      float p =
          fmaf(pam_b[l], att_w[HD + l], pam_b[l + 64] * att_w[HD + 64 + l]);
      p = wave_allsum(p);
      if (l == 0) consts[1] = p;
    }
    return;
  }
  const int t = blockIdx.x * 256 + threadIdx.x;
  const float* W;
  u16* dst;
  if (t < 2048) {  // gcn_w: K=128 -> 16 kb
    const int kb = t >> 7, n = t & 127;
    W = gcn_w + (size_t)kb * 8 * HD + n;
    dst = Bg + (size_t)t * 8;
  } else if (t < 6144) {  // [pam_w; pm_w2]: K=256 -> 32 kb
    const int u = t - 2048;
    const int kb = u >> 7, n = u & 127;
    W = ((kb < 16) ? (pam_w + (size_t)kb * 8 * HD)
                   : (pm_w2 + (size_t)(kb - 16) * 8 * HD)) +
        n;
    dst = Bl + (size_t)u * 8;
  } else {  // fus_w: K=256 -> 32 kb
    const int u = t - 6144;
    const int kb = u >> 7, n = u & 127;
    W = fus_w + (size_t)kb * 8 * HD + n;
    dst = Bf + (size_t)u * 8;
  }
  union {
    u16 o[8];
    uint4 v;
  } pk;
#pragma unroll
  for (int i = 0; i < 8; ++i) pk.o[i] = (u16)f2b_bits(W[i * HD]);
  *(uint4*)dst = pk.v;
}

// ---- per-256-block sums of cnt ----
__global__ __launch_bounds__(256) void k_scan1(const int* __restrict__ cnt,
                                               int* __restrict__ bsum) {
  const int i = blockIdx.x * 256 + threadIdx.x;
  int v = (i < NN) ? cnt[i] : 0;
#pragma unroll
  for (int m = 1; m < 64; m <<= 1) v += __shfl_xor(v, m, 64);
  __shared__ int s[4];
  if ((threadIdx.x & 63) == 0) s[threadIdx.x >> 6] = v;
  __syncthreads();
  if (threadIdx.x == 0) bsum[blockIdx.x] = s[0] + s[1] + s[2] + s[3];
}

// ---- merged scan2+scan3: emits offs, dinv ----
__global__ __launch_bounds__(256) void k_scan23(
    const int* __restrict__ cnt, const int* __restrict__ bsum,
    int* __restrict__ offs, float* __restrict__ dinv) {
  __shared__ int s[256];
  const int t = threadIdx.x;
  const int bv = (t < SCAN_B) ? bsum[t] : 0;
  s[t] = bv;
  __syncthreads();
  for (int d = 1; d < 256; d <<= 1) {
    int add = (t >= d) ? s[t - d] : 0;
    __syncthreads();
    s[t] += add;
    __syncthreads();
  }
  const int bpre = (blockIdx.x > 0) ? s[blockIdx.x - 1] : 0;
  __syncthreads();
  const int i = blockIdx.x * 256 + t;
  const int v = (i < NN) ? cnt[i] : 0;
  s[t] = v;
  __syncthreads();
  for (int d = 1; d < 256; d <<= 1) {
    int add = (t >= d) ? s[t - d] : 0;
    __syncthreads();
    s[t] += add;
    __syncthreads();
  }
  if (i < NN) {
    offs[i] = bpre + s[t] - v;
    dinv[i] = __builtin_amdgcn_rsqf((float)v + 1.0f);
  }
}

// ---- merged: CSR scatter (u16, no atomics) | graph counts | node pass ----
__global__ __launch_bounds__(256) void k_scatgc(
    const int* __restrict__ ei, const int* __restrict__ offs,
    const u16* __restrict__ slot16, u16* __restrict__ csr16,
    const int* __restrict__ batch, float* __restrict__ counts,
    const float* __restrict__ x, const float* __restrict__ pos,
    const int* __restrict__ cnt, const float* __restrict__ vi,
    const float* __restrict__ vj, const float* __restrict__ consts,
    u16* __restrict__ xq, float* __restrict__ ai_arr,
    float4* __restrict__ posadj) {
  if (blockIdx.x < HIST_B) {  // scatter: plain u16 stores (L2-resident)
    const int e = blockIdx.x * 256 + threadIdx.x;
    if (e < NE) {
      const int d = ei[NE + e];
      csr16[offs[d] + slot16[e]] = (u16)ei[e];
    }
    return;
  }
  if (blockIdx.x == HIST_B) {  // graph counts via binary search
    const int g = threadIdx.x;
    int lo = 0, hi = NN;
    while (lo < hi) {
      const int mid = (lo + hi) >> 1;
      if (batch[mid] < g) lo = mid + 1; else hi = mid;
    }
    const int b0 = lo;
    hi = NN;
    while (lo < hi) {
      const int mid = (lo + hi) >> 1;
      if (batch[mid] <= g) lo = mid + 1; else hi = mid;
    }
    counts[g] = (float)(lo - b0);
    return;
  }
  // node pass: y = dinv*x (FP8 e4m3), ai, posadj = {x,y,z, f16{aj,sdeg}}
  const int wave = threadIdx.x >> 6, lane = threadIdx.x & 63;
  const int i = (blockIdx.x - HIST_B - 1) * 4 + wave;
  if (i >= NN) return;
  const float2 v = *(const float2*)&x[(size_t)i * HD + lane * 2];
  const int c = cnt[i];
  const float dv = __builtin_amdgcn_rsqf((float)c + 1.0f);
  const u32 q = __builtin_amdgcn_cvt_pk_fp8_f32(dv * v.x, dv * v.y, 0u, false);
  xq[(size_t)i * 64 + lane] = (u16)q;
  const float2 a = *(const float2*)&vi[lane * 2];
  const float2 b = *(const float2*)&vj[lane * 2];
  float si = wave_allsum(fmaf(v.x, a.x, v.y * a.y));
  float sj = wave_allsum(fmaf(v.x, b.x, v.y * b.y));
  if (lane == 0) {
    ai_arr[i] = si + consts[0];
    const u32 wb =
        (u32)__half_as_ushort(__float2half(sj + consts[1])) |
        ((u32)__half_as_ushort(__float2half(sqrtf((float)c + 1.f))) << 16);
    posadj[i] = make_float4(pos[3 * i], pos[3 * i + 1], pos[3 * i + 2],
                            __uint_as_float(wb));
  }
}

// ------------- per-node edge aggregation (1 wave / node) -------------------
// R14/R15 best-measured variant; csr u16.
__global__ __launch_bounds__(256) void k_agg(
    const u16* __restrict__ xq, const float4* __restrict__ posadj,
    const u16* __restrict__ csr16, const int* __restrict__ offs,
    const int* __restrict__ cnt, const float* __restrict__ ai_arr,
    const float* __restrict__ pm_w1, const float* __restrict__ pm_b1,
    u32* __restrict__ ZG, u32* __restrict__ XT, float* __restrict__ sa_out) {
  const int wave = threadIdx.x >> 6, lane = threadIdx.x & 63;
  const int i = blockIdx.x * 4 + wave;
  if (i >= NN) return;
  const int c0 = lane * 2;

  const f32x2 w1x = *(const f32x2*)&pm_w1[c0];
  const f32x2 w1y = *(const f32x2*)&pm_w1[HD + c0];
  const f32x2 w1z = *(const f32x2*)&pm_w1[2 * HD + c0];
  const f32x2 b1 = *(const f32x2*)&pm_b1[c0];
  const float ai = ai_arr[i];
  const float4 pi = posadj[i];

  f32x2 zg = {0.f, 0.f}, xa = {0.f, 0.f}, tt = {0.f, 0.f};
  float sa = 0.f;
  const int b = offs[i], e = b + cnt[i];
  for (int base = b; base < e; base += 64) {
    const int mm = min(64, e - base);
    const int sk = (int)csr16[base + ((lane < mm) ? lane : 0)];
    const float4 pa = posadj[sk];  // one scattered 16B gather per edge
    const u32 wb = __float_as_uint(pa.w);
    const float aj = __half2float(__ushort_as_half((u16)(wb & 0xffffu)));
    const float sdeg = __half2float(__ushort_as_half((u16)(wb >> 16)));
    float attk = __builtin_amdgcn_rcpf(1.f + __expf(-(ai + aj)));
    const float apk = attk * sdeg;  // att' = att*sdeg
    const float dxk = pi.x - pa.x;
    const float dyk = pi.y - pa.y;
    const float dzk = pi.z - pa.z;
    if (lane >= mm) attk = 0.f;
    sa += wave_allsum(attk);

    for (int s16 = 0; s16 < mm; s16 += 16) {
      const int n16 = min(16, mm - s16);
      u32 rr[16];
#pragma unroll
      for (int u = 0; u < 16; ++u) {
        if (u < n16) {
          const int s = __builtin_amdgcn_readlane(sk, s16 + u);
          rr[u] = *(xq + ((size_t)s << 6) + lane);  // uniform base + lane
        }
      }
#pragma unroll
      for (int u = 0; u < 16; ++u) {
        if (u < n16) {
          const int T = s16 + u;
          const float att = bcastf(attk, T);
          const float ap = bcastf(apk, T);
          const float dx = bcastf(dxk, T);
          const float dy = bcastf(dyk, T);
          const float dz = bcastf(dzk, T);
          const f32x2 y = __builtin_amdgcn_cvt_pk_f32_fp8(rr[u], false);
          zg += y;
          xa = pkfma(splat2(ap), y, xa);
          f32x2 gg = pkfma(splat2(dz), w1z,
                           pkfma(splat2(dy), w1y,
                                 pkfma(splat2(dx), w1x, b1)));
          gg = __builtin_elementwise_max(gg, splat2(0.f));
          tt = pkfma(splat2(att), gg, tt);
        }
      }
    }
  }
  const u32 xi = *(xq + ((size_t)i << 6) + lane);  // self term: y_i
  zg += __builtin_amdgcn_cvt_pk_f32_fp8(xi, false);

  ZG[(size_t)i * 64 + lane] = cvtpk_bf16(zg.x, zg.y);
  XT[(size_t)i * 128 + lane] = cvtpk_bf16(xa.x, xa.y);
  XT[(size_t)i * 128 + 64 + lane] = cvtpk_bf16(tt.x, tt.y);
  if (lane == 0) sa_out[i] = sa;
}

// ---- GEMM phase with DEPTH-2 prefetch (3-buffer ping-pong, static idx). ----
template <int K16>
__device__ __forceinline__ void phase_g2(const u16* __restrict__ pa,
                                         const u16* __restrict__ pb0,
                                         f32x4 acc[8]) {
  bf16x8 a[3], b[3][8];
#pragma unroll
  for (int p = 0; p < 2; ++p) {  // prologue: k0=0,1 in flight (K16 >= 2)
    a[p] = *(const bf16x8*)(pa + p * 32);
    const u16* pn = pb0 + (size_t)p * 4096;
#pragma unroll
    for (int cf = 0; cf < 8; ++cf) b[p][cf] = *(const bf16x8*)(pn + cf * 128);
  }
#pragma unroll
  for (int k0 = 0; k0 < K16; ++k0) {
    if (k0 + 2 < K16) {
      const int nb = (k0 + 2) % 3;
      a[nb] = *(const bf16x8*)(pa + (k0 + 2) * 32);
      const u16* pn = pb0 + (size_t)(k0 + 2) * 4096;
#pragma unroll
      for (int cf = 0; cf < 8; ++cf)
        b[nb][cf] = *(const bf16x8*)(pn + cf * 128);
    }
    const int cb = k0 % 3;
#pragma unroll
    for (int cf = 0; cf < 8; ++cf)
      acc[cf] = __builtin_amdgcn_mfma_f32_16x16x32_bf16(a[cb], b[cb][cf],
                                                        acc[cf], 0, 0, 0);
  }
}

// ---- fused dense tail, 64-row tiles, 4 waves, each wave owns 16 rows ----
__global__ __launch_bounds__(256, 3) void k_gemms(
    const u16* __restrict__ ZG, const u16* __restrict__ XT,
    const u16* __restrict__ Bg, const u16* __restrict__ Bl,
    const u16* __restrict__ Bf, const float* __restrict__ dinv,
    const float* __restrict__ sa, const float* __restrict__ gcn_b,
    const float* __restrict__ bsumv, const float* __restrict__ fus_b,
    const int* __restrict__ batch, float* __restrict__ pooled) {
  __shared__ u16 T[64 * 256];  // 32KB bf16 [gl|local]; reused as f32 F[64][128]
  __shared__ int batch_lds[64];
  const int n0 = blockIdx.x * 64;
  const int t = threadIdx.x, lane = t & 63, w = t >> 6;
  const int m = lane & 15, g = lane >> 4;
  const int r0 = w * 16;

  if (t < 64) batch_lds[t] = (n0 + t < NN) ? batch[n0 + t] : -1;

  const int rowA = min(n0 + r0 + m, NN - 1);
  f32x4 acc[8];

  // ---- phase A: gl = relu(dinv*(ZG@gcn_w) + gcn_b) -> T cols 0..127 ----
#pragma unroll
  for (int cf = 0; cf < 8; ++cf) acc[cf] = (f32x4){0.f, 0.f, 0.f, 0.f};
  phase_g2<4>(ZG + (size_t)rowA * 128 + g * 8, Bg + ((size_t)g * HD + m) * 8,
              acc);
#pragma unroll
  for (int j = 0; j < 4; ++j) {
    const int rl = r0 + g * 4 + j;
    const float dv = dinv[min(n0 + rl, NN - 1)];
#pragma unroll
    for (int cf = 0; cf < 8; ++cf) {
      const float v = fmaxf(fmaf(dv, acc[cf][j], gcn_b[cf * 16 + m]), 0.f);
      T[rl * 256 + ((cf * 16 + m) ^ ((rl & 7) << 3))] = (u16)f2b_bits(v);
    }
  }

  // ---- phase B: local = relu(XT@Bl + sa*bsum) -> T cols 128..255 ----
#pragma unroll
  for (int cf = 0; cf < 8; ++cf) acc[cf] = (f32x4){0.f, 0.f, 0.f, 0.f};
  phase_g2<8>(XT + (size_t)rowA * 256 + g * 8, Bl + ((size_t)g * HD + m) * 8,
              acc);
#pragma unroll
  for (int j = 0; j < 4; ++j) {
    const int rl = r0 + g * 4 + j;
    const float sv = sa[min(n0 + rl, NN - 1)];
#pragma unroll
    for (int cf = 0; cf < 8; ++cf) {
      const float v = fmaxf(fmaf(sv, bsumv[cf * 16 + m], acc[cf][j]), 0.f);
      T[rl * 256 + ((128 + cf * 16 + m) ^ ((rl & 7) << 3))] = (u16)f2b_bits(v);
    }
  }

  // ---- phase C: fused = relu([gl|local]@fus_w + fus_b), A from LDS (own
  //      rows; no barrier needed), depth-2 B prefetch ----
  const int x0m = (m & 7) << 3;
  const u16* rowT = &T[(r0 + m) * 256];
  const u16* pbC = Bf + ((size_t)g * HD + m) * 8;
#pragma unroll
  for (int cf = 0; cf < 8; ++cf) acc[cf] = (f32x4){0.f, 0.f, 0.f, 0.f};
  {
    bf16x8 a[3], b[3][8];
#pragma unroll
    for (int p = 0; p < 2; ++p) {
      a[p] = *(const bf16x8*)&rowT[(g * 8 + p * 32) ^ x0m];
      const u16* pn = pbC + (size_t)p * 4096;
#pragma unroll
      for (int cf = 0; cf < 8; ++cf) b[p][cf] = *(const bf16x8*)(pn + cf * 128);
    }
#pragma unroll
    for (int k0 = 0; k0 < 8; ++k0) {
      if (k0 + 2 < 8) {
        const int nb = (k0 + 2) % 3;
        a[nb] = *(const bf16x8*)&rowT[(g * 8 + (k0 + 2) * 32) ^ x0m];
        const u16* pn = pbC + (size_t)(k0 + 2) * 4096;
#pragma unroll
        for (int cf = 0; cf < 8; ++cf)
          b[nb][cf] = *(const bf16x8*)(pn + cf * 128);
      }
      const int cb = k0 % 3;
#pragma unroll
      for (int cf = 0; cf < 8; ++cf)
        acc[cf] = __builtin_amdgcn_mfma_f32_16x16x32_bf16(a[cb], b[cb][cf],
                                                          acc[cf], 0, 0, 0);
    }
  }
  float* F = (float*)T;  // overwrite own rows only
#pragma unroll
  for (int j = 0; j < 4; ++j) {
    const int rl = r0 + g * 4 + j;
#pragma unroll
    for (int cf = 0; cf < 8; ++cf)
      F[rl * 128 + ((cf * 16 + m) ^ ((rl & 12) << 2))] =
          fmaxf(acc[cf][j] + fus_b[cf * 16 + m], 0.f);
  }
  __syncthreads();

  // ---- segment pooling over sorted batch ids ----
  const int col = t & 127;
  const int q = t >> 7;
  int seg = -1;
  float run = 0.f;
  for (int r = q * 32; r < q * 32 + 32; ++r) {
    const int bg = batch_lds[r];
    const float v = F[r * 128 + (col ^ ((r & 12) << 2))];
    if (bg != seg) {
      if (seg >= 0) atomicAdd(&pooled[seg * HD + col], run);
      seg = bg;
      run = 0.f;
    }
    if (bg >= 0) run += v;
  }
  if (seg >= 0) atomicAdd(&pooled[seg * HD + col], run);
}

// ---------------- head: out = relu(pooled/cnt @ l1)@l2 ----------------
__global__ __launch_bounds__(64) void k_head(const float* __restrict__ pooled,
                                             const float* __restrict__ counts,
                                             const float* __restrict__ l1w,
                                             const float* __restrict__ l1b,
                                             const float* __restrict__ l2w,
                                             const float* __restrict__ l2b,
                                             float* __restrict__ out) {
  const int g = blockIdx.x, j = threadIdx.x;
  const float inv = __builtin_amdgcn_rcpf(fmaxf(counts[g], 1.f));
  float acc = l1b[j];
  for (int k = 0; k < HD; ++k)
    acc = fmaf(pooled[g * HD + k] * inv, l1w[k * 64 + j], acc);
  float v = fmaxf(acc, 0.f) * l2w[j];
  v = wave_allsum(v);
  if (j == 0) out[g] = v + l2b[0];
}

extern "C" void kernel_launch(void* const* d_in, const int* in_sizes, int n_in,
                              void* d_out, int out_size, void* d_ws,
                              size_t ws_size, hipStream_t stream) {
  const float* x = (const float*)d_in[0];
  const float* pos = (const float*)d_in[1];
  const int* ei = (const int*)d_in[2];
  const int* batch = (const int*)d_in[3];
  const float* gcn_w = (const float*)d_in[4];
  const float* gcn_b = (const float*)d_in[5];
  const float* pam_w = (const float*)d_in[6];
  const float* pam_b = (const float*)d_in[7];
  const float* pm_w1 = (const float*)d_in[8];
  const float* pm_b1 = (const float*)d_in[9];
  const float* pm_w2 = (const float*)d_in[10];
  const float* pm_b2 = (const float*)d_in[11];
  const float* att_w = (const float*)d_in[12];
  const float* att_b = (const float*)d_in[13];
  const float* fus_w = (const float*)d_in[14];
  const float* fus_b = (const float*)d_in[15];
  const float* l1_w = (const float*)d_in[16];
  const float* l1_b = (const float*)d_in[17];
  const float* l2_w = (const float*)d_in[18];
  const float* l2_b = (const float*)d_in[19];
  float* out = (float*)d_out;

  size_t off = 0;
  auto alloc = [&](size_t bytes) {
    void* p = (char*)d_ws + off;
    off += (bytes + 255) & ~size_t(255);
    return p;
  };
  u16* xq = (u16*)alloc((size_t)NN * 64 * 2);  // y = dinv*x, fp8 e4m3 (6.4MB)
  u32* ZG = (u32*)alloc((size_t)NN * 64 * 4);
  u32* XT = (u32*)alloc((size_t)NN * 128 * 4);
  float* sa = (float*)alloc((size_t)NN * 4);
  float* ai = (float*)alloc((size_t)NN * 4);
  float* dinv = (float*)alloc((size_t)NN * 4);
  float4* posadj = (float4*)alloc((size_t)NN * 16);  // {x,y,z, f16{aj,sdeg}}
  float* pooled = (float*)alloc((size_t)NG * HD * 4);
  float* counts = (float*)alloc((size_t)NG * 4);
  int* cnt = (int*)alloc((size_t)NN * 4);  // zeroed via memsetAsync
  int* offs = (int*)alloc((size_t)NN * 4);
  u16* csr16 = (u16*)alloc((size_t)NE * 2);
  u16* slot16 = (u16*)alloc((size_t)NE * 2);
  int* bsum = (int*)alloc((size_t)SCAN_B * 4);
  u16* Bg = (u16*)alloc((size_t)16 * 128 * 8 * 2);
  u16* Bl = (u16*)alloc((size_t)32 * 128 * 8 * 2);
  u16* Bf = (u16*)alloc((size_t)32 * 128 * 8 * 2);
  float* vi = (float*)alloc(128 * 4);
  float* vj = (float*)alloc(128 * 4);
  float* consts = (float*)alloc(2 * 4);
  float* bsumv = (float*)alloc(128 * 4);

  hipMemsetAsync(cnt, 0, NN * 4, stream);
  k_wpack<<<WP_HIST0 + HIST_B, 256, 0, stream>>>(
      gcn_w, pam_w, pm_w2, fus_w, pam_b, att_w, att_b, pm_b2, Bg, Bl, Bf, vi,
      vj, consts, bsumv, (uint4*)pooled, ei, cnt, slot16);
  k_scan1<<<SCAN_B, 256, 0, stream>>>(cnt, bsum);
  k_scan23<<<SCAN_B, 256, 0, stream>>>(cnt, bsum, offs, dinv);
  k_scatgc<<<HIST_B + 1 + NODE_B, 256, 0, stream>>>(
      ei, offs, slot16, csr16, batch, counts, x, pos, cnt, vi, vj, consts, xq,
      ai, posadj);
  k_agg<<<NODE_B, 256, 0, stream>>>(xq, posadj, csr16, offs, cnt, ai, pm_w1,
                                    pm_b1, ZG, XT, sa);
  k_gemms<<<GEM_B, 256, 0, stream>>>((const u16*)ZG, (const u16*)XT, Bg, Bl,
                                     Bf, dinv, sa, gcn_b, bsumv, fus_b, batch,
                                     pooled);
  k_head<<<NG, 64, 0, stream>>>(pooled, counts, l1_w, l1_b, l2_w, l2_b, out);
}